// Round 1
// baseline (35.888 us; speedup 1.0000x reference)
//
#include <hip/hip_runtime.h>

// DWT(level2) followed by IDWT(level2) with the same detail coefficients is
// the exact identity (orthonormal Haar, 0.5 scale factors are exact in fp32):
//   LL-LH-HL+HH = 2a, LL-LH+HL-HH = 2b, LL+LH-HL-HH = 2c, LL+LH+HL+HH = 2d.
// Reference output == x up to fp32 addition rounding (~1e-5 << 1.08e-1 thr).
// Optimal kernel: memory-bound float4 copy of x -> out.

__global__ __launch_bounds__(256) void dwt_identity_copy(
    const float4* __restrict__ in, float4* __restrict__ out, long long n4) {
    long long i = (long long)blockIdx.x * blockDim.x + threadIdx.x;
    long long stride = (long long)gridDim.x * blockDim.x;
    for (; i < n4; i += stride) {
        out[i] = in[i];
    }
}

extern "C" void kernel_launch(void* const* d_in, const int* in_sizes, int n_in,
                              void* d_out, int out_size, void* d_ws, size_t ws_size,
                              hipStream_t stream) {
    const float* x = (const float*)d_in[0];
    float* out = (float*)d_out;

    // out_size = 32*3*512*512 = 25,165,824 floats; divisible by 4.
    long long n4 = (long long)out_size / 4;

    const int block = 256;
    int grid = 2048;  // 256 CUs * 8 blocks/CU; grid-stride covers the rest
    long long needed = (n4 + block - 1) / block;
    if (needed < grid) grid = (int)needed;

    dwt_identity_copy<<<grid, block, 0, stream>>>(
        (const float4*)x, (float4*)out, n4);
}

// Round 2
// 33.408 us; speedup vs baseline: 1.0742x; 1.0742x over previous
//
#include <hip/hip_runtime.h>

// DWT(level2)+IDWT(level2) with the same detail coefficients is the exact
// identity (orthonormal Haar; all 0.5 scales exact in fp32):
//   LL-LH-HL+HH = 2a, LL-LH+HL-HH = 2b, LL+LH-HL-HH = 2c, LL+LH+HL+HH = 2d.
// Reference output == x up to fp32 addition rounding (~1e-5 << 1.08e-1 thr).
// Optimal kernel: pure D2D copy. Use the vendor blit path (hipMemcpyAsync is
// graph-capture-safe per the harness) which sustains ~6.8-7.0 TB/s vs our
// hand-rolled float4 kernel's 5.6 TB/s.

extern "C" void kernel_launch(void* const* d_in, const int* in_sizes, int n_in,
                              void* d_out, int out_size, void* d_ws, size_t ws_size,
                              hipStream_t stream) {
    const float* x = (const float*)d_in[0];
    float* out = (float*)d_out;
    size_t bytes = (size_t)out_size * sizeof(float);
    hipMemcpyAsync(out, x, bytes, hipMemcpyDeviceToDevice, stream);
}